// Round 7
// baseline (280.002 us; speedup 1.0000x reference)
//
#include <hip/hip_runtime.h>
#include <hip/hip_bf16.h>

#define B_ 32
#define T_ 512
#define TP_ 514          /* padded rows per batch */
#define L_ 2048
#define H_ 512
#define NRR (B_*T_)      /* 16384 rows */
#define KC_ 1536         /* 3*H */
#define NB_ 256
#define EPS_ 1e-5f
#define XPE ((size_t)B_ * TP_ * H_)   /* elems per padded buffer */

typedef __bf16 bf16;
typedef __bf16 bf16x8 __attribute__((ext_vector_type(8)));
typedef float f32x4 __attribute__((ext_vector_type(4)));

static const size_t WC_BYTES  = (size_t)6 * H_ * KC_ * 2;       // 9,437,184
static const size_t XP_BYTES  = XPE * 2;                        // 16,842,752
static const size_t Y_BYTES   = (size_t)3 * NRR * H_ * 2;       // 50,331,648

__device__ __forceinline__ void gload16(const void* g, void* l) {
    __builtin_amdgcn_global_load_lds(
        (const __attribute__((address_space(1))) unsigned int*)g,
        (__attribute__((address_space(3))) unsigned int*)l, 16, 0, 0);
}

#define SB() __builtin_amdgcn_sched_barrier(0)
#define BAR() do { SB(); asm volatile("" ::: "memory"); __builtin_amdgcn_s_barrier(); SB(); } while(0)
#define VMCNT(N) do { asm volatile("s_waitcnt vmcnt(" #N ")" ::: "memory"); SB(); } while(0)

// ---------------- weight repack: w[i][o][c][k] -> Wc[m][o][k*H + c] (bf16) ----
__global__ void k_prep_wc(const float* __restrict__ wd, const float* __restrict__ wp,
                          const float* __restrict__ we, bf16* __restrict__ wc) {
    int e = blockIdx.x * 256 + threadIdx.x;
    if (e >= 6 * H_ * KC_) return;
    int m   = e / (H_ * KC_);
    int rem = e % (H_ * KC_);
    int o  = rem / KC_;
    int r2 = rem % KC_;
    int k  = r2 / H_;
    int c  = r2 % H_;
    int p = m >> 1, i = m & 1;
    const float* w = (p == 0) ? wd : (p == 1 ? wp : we);
    float v = w[((size_t)i * H_ * H_ + (size_t)o * H_ + c) * 3 + k];
    wc[e] = (bf16)v;
}

// ---------------- padded bf16 input + zero pad rows of the 3 xp1 buffers -----
__global__ void k_pad(const float* __restrict__ x, bf16* __restrict__ xp0,
                      bf16* __restrict__ xp1) {
    int wid = threadIdx.x >> 6, lane = threadIdx.x & 63;
    int row = blockIdx.x * 4 + wid;               // 0 .. 32*514-1
    int b = row / TP_, tp = row % TP_;
    bf16* d0 = xp0 + (size_t)row * H_ + lane * 8;
    if (tp == 0 || tp == TP_ - 1) {
        bf16x8 z;
#pragma unroll
        for (int i = 0; i < 8; ++i) z[i] = (bf16)0.0f;
        *(bf16x8*)d0 = z;
#pragma unroll
        for (int p = 0; p < 3; ++p)
            *(bf16x8*)(xp1 + p * XPE + (size_t)row * H_ + lane * 8) = z;
    } else {
        const f32x4* p = (const f32x4*)(x + ((size_t)(b * T_ + tp - 1)) * H_ + lane * 8);
        f32x4 u = p[0], v = p[1];
        bf16x8 o;
        o[0] = (bf16)u[0]; o[1] = (bf16)u[1]; o[2] = (bf16)u[2]; o[3] = (bf16)u[3];
        o[4] = (bf16)v[0]; o[5] = (bf16)v[1]; o[6] = (bf16)v[2]; o[7] = (bf16)v[3];
        *(bf16x8*)d0 = o;
    }
}

// ---------------- per-batch inclusive scan of durations ----------------------
__global__ void k_scan(const int* __restrict__ dur, int* __restrict__ csum,
                       float* __restrict__ mel_out) {
    int b = blockIdx.x, t = threadIdx.x;
    __shared__ int s[T_];
    s[t] = dur[b * T_ + t];
    __syncthreads();
    for (int off = 1; off < T_; off <<= 1) {
        int v = (t >= off) ? s[t - off] : 0;
        __syncthreads();
        s[t] += v;
        __syncthreads();
    }
    csum[b * T_ + t] = s[t];
    if (t == T_ - 1) mel_out[b] = (float)((s[t] < L_) ? s[t] : L_);
}

// -------- length regulate + inline bucketize + (x + p_emb + e_emb) gather ----
__global__ void k_gather(const float* __restrict__ x, const float* __restrict__ pemb,
                         const float* __restrict__ eemb, const float* __restrict__ pt,
                         const float* __restrict__ et, const float* __restrict__ pbins,
                         const float* __restrict__ ebins, const int* __restrict__ csum,
                         float* __restrict__ out) {
    int bi = blockIdx.x;
    int b  = bi >> 9;
    int l0 = (bi & 511) << 2;
    __shared__ int cs[T_];
    __shared__ float pb[NB_ - 1], eb[NB_ - 1];
    cs[threadIdx.x]       = csum[b * T_ + threadIdx.x];
    cs[threadIdx.x + 256] = csum[b * T_ + threadIdx.x + 256];
    if (threadIdx.x < NB_ - 1) {
        pb[threadIdx.x] = pbins[threadIdx.x];
        eb[threadIdx.x] = ebins[threadIdx.x];
    }
    __syncthreads();
    int wid = threadIdx.x >> 6, lane = threadIdx.x & 63;
    int l = l0 + wid;
    int mel = cs[T_ - 1]; if (mel > L_) mel = L_;
    float* op = out + ((size_t)(b * L_ + l)) * H_ + lane * 8;
    if (l >= mel) {
        f32x4 z = {0.f, 0.f, 0.f, 0.f};
        ((f32x4*)op)[0] = z;
        ((f32x4*)op)[1] = z;
        return;
    }
    int lo = 0, hi = T_;
    while (lo < hi) { int mid = (lo + hi) >> 1; if (cs[mid] <= l) lo = mid + 1; else hi = mid; }
    int idx = (lo < T_ - 1) ? lo : (T_ - 1);
    int rr = b * T_ + idx;
    float pv = pt[rr], ev = et[rr];
    int pi, ei;
    { int a = 0, c = NB_ - 1; while (a < c) { int mid = (a + c) >> 1; if (pb[mid] < pv) a = mid + 1; else c = mid; } pi = a; }
    { int a = 0, c = NB_ - 1; while (a < c) { int mid = (a + c) >> 1; if (eb[mid] < ev) a = mid + 1; else c = mid; } ei = a; }
    const f32x4* xp = (const f32x4*)(x    + (size_t)rr * H_ + lane * 8);
    const f32x4* pp = (const f32x4*)(pemb + (size_t)pi * H_ + lane * 8);
    const f32x4* ep = (const f32x4*)(eemb + (size_t)ei * H_ + lane * 8);
    ((f32x4*)op)[0] = xp[0] + pp[0] + ep[0];
    ((f32x4*)op)[1] = xp[1] + pp[1] + ep[1];
}

// ================= 8-phase 256x256x(BK=64) conv-as-GEMM ======================
// 8 waves (2M x 4N), per-wave out 128x64. Per phase: all waves compute ONE
// 128x128 C-quadrant (16 MFMA/wave). Phases (mh,nh): (0,0),(0,1),(1,0),(1,1).
// LDS 128KB: [2 buf][ A 256x64 | B 256x64 ], T2 source-side 16B-chunk swizzle.
// Stage 1 half-tile/phase (2 gload_lds): P1:A1(t+1) P2:A0(t+2) P3:B0(t+2)
// P4:B1(t+2); vmcnt(6) once per K-tile (3 half-tiles in flight). T1 XCD-chunk.
template<int LAYER>
__global__ __launch_bounds__(512, 2)
void k_gemm(const bf16* __restrict__ Xp, const bf16* __restrict__ Wall,
            const float* __restrict__ cb0, const float* __restrict__ cb1,
            const float* __restrict__ cb2, bf16* __restrict__ Y) {
    __shared__ bf16 lds[65536];     // 128 KB

    int bid = blockIdx.x;
    int swz = (bid & 7) * 48 + (bid >> 3);      // 384 = 8 * 48
    int rowblk = swz / 6, colblk = swz % 6;
    int p  = colblk >> 1;
    int oB = (colblk & 1) * 256;
    int rowBase = rowblk * 256;

    const bf16* A = (LAYER == 0) ? Xp : (Xp + (size_t)p * XPE);
    const bf16* W = Wall + ((size_t)(2 * p + LAYER) * H_ + oB) * KC_;
    const float* cbp  = (p == 0) ? cb0 : (p == 1 ? cb1 : cb2);
    const float* bias = cbp + LAYER * H_;

    int tid = threadIdx.x;
    int wid = tid >> 6, lane = tid & 63;
    int wm = wid >> 2, wn = wid & 3;
    int lr = lane & 15, kq = lane >> 4, xk = lr & 7;
    int srow8 = lane >> 3;
    int csw = ((lane & 7) ^ srow8) << 3;        // T2 pre-swizzled source col
    int b = rowBase >> 9, t0 = rowBase & (T_ - 1);
    const bf16* Abase = A + ((size_t)(b * TP_ + t0)) * H_;

    f32x4 acc00[4][2], acc01[4][2], acc10[4][2], acc11[4][2];
#pragma unroll
    for (int i = 0; i < 4; ++i)
#pragma unroll
        for (int j = 0; j < 2; ++j) {
            acc00[i][j] = (f32x4){0.f,0.f,0.f,0.f}; acc01[i][j] = (f32x4){0.f,0.f,0.f,0.f};
            acc10[i][j] = (f32x4){0.f,0.f,0.f,0.f}; acc11[i][j] = (f32x4){0.f,0.f,0.f,0.f};
        }
    bf16x8 afr[4][2], bfr[2][2][2];

#define STAGE_A(TAU, MH, D) do { \
    int k_ = (TAU) >> 3; int c0_ = ((TAU) & 7) << 6; \
    const bf16* s_ = Abase + ((size_t)(k_ + (MH)*128 + wid*8 + srow8)) * H_ + c0_ + csw; \
    gload16(s_,                   &lds[(D)*32768 + (MH)*8192 + wid*512]); \
    gload16(s_ + (size_t)64 * H_, &lds[(D)*32768 + (MH)*8192 + 4096 + wid*512]); \
} while (0)

#define STAGE_B(TAU, NH, D) do { \
    const bf16* s_ = W + ((size_t)((NH)*128 + wid*8 + srow8)) * KC_ + (TAU)*64 + csw; \
    gload16(s_,                    &lds[(D)*32768 + 16384 + (NH)*8192 + wid*512]); \
    gload16(s_ + (size_t)64 * KC_, &lds[(D)*32768 + 16384 + (NH)*8192 + 4096 + wid*512]); \
} while (0)

#define LOAD_A(MH, D) do { \
    _Pragma("unroll") for (int i_ = 0; i_ < 4; ++i_) \
    _Pragma("unroll") for (int kk_ = 0; kk_ < 2; ++kk_) \
        afr[i_][kk_] = *(const bf16x8*)&lds[(D)*32768 + (MH)*8192 + \
            ((wm*4 + i_)*16 + lr)*64 + (((kk_*4 + kq) ^ xk) << 3)]; \
} while (0)

#define LOAD_B(NH, D) do { \
    _Pragma("unroll") for (int j_ = 0; j_ < 2; ++j_) \
    _Pragma("unroll") for (int kk_ = 0; kk_ < 2; ++kk_) \
        bfr[NH][j_][kk_] = *(const bf16x8*)&lds[(D)*32768 + 16384 + (NH)*8192 + \
            ((wn*2 + j_)*16 + lr)*64 + (((kk_*4 + kq) ^ xk) << 3)]; \
} while (0)

#define MFMA_Q(ACC, NH) do { \
    __builtin_amdgcn_s_setprio(1); \
    _Pragma("unroll") for (int i_ = 0; i_ < 4; ++i_) \
    _Pragma("unroll") for (int j_ = 0; j_ < 2; ++j_) \
    _Pragma("unroll") for (int kk_ = 0; kk_ < 2; ++kk_) \
        ACC[i_][j_] = __builtin_amdgcn_mfma_f32_16x16x32_bf16(afr[i_][kk_], bfr[NH][j_][kk_], ACC[i_][j_], 0, 0, 0); \
    __builtin_amdgcn_s_setprio(0); \
} while (0)

#define KTILE(TAU, D, S1, S2, S3, S4, VMA) do { \
    LOAD_A(0, D); LOAD_B(0, D); S1; BAR(); MFMA_Q(acc00, 0); BAR(); \
    LOAD_B(1, D);               S2; BAR(); MFMA_Q(acc01, 1); BAR(); \
    LOAD_A(1, D);               S3; BAR(); MFMA_Q(acc10, 0); BAR(); \
                                S4; BAR(); MFMA_Q(acc11, 1); VMA; BAR(); \
} while (0)

    // prologue: issue order = steady-state age order
    STAGE_A(0, 0, 0); STAGE_B(0, 0, 0); STAGE_B(0, 1, 0); STAGE_A(0, 1, 0);
    STAGE_A(1, 0, 1); STAGE_B(1, 0, 1); STAGE_B(1, 1, 1);
    VMCNT(6);            // tile 0 fully landed; 3 half-tiles of tile 1 in flight
    BAR();

#pragma unroll 1
    for (int it = 0; it < 11; ++it) {
        int ta = 2 * it, tb = 2 * it + 1;
        KTILE(ta, 0, STAGE_A(ta + 1, 1, 1), STAGE_A(ta + 2, 0, 0),
                     STAGE_B(ta + 2, 0, 0), STAGE_B(ta + 2, 1, 0), VMCNT(6));
        KTILE(tb, 1, STAGE_A(tb + 1, 1, 0), STAGE_A(tb + 2, 0, 1),
                     STAGE_B(tb + 2, 0, 1), STAGE_B(tb + 2, 1, 1), VMCNT(6));
    }
    // tail: tiles 22, 23
    KTILE(22, 0, STAGE_A(23, 1, 1), (void)0, (void)0, (void)0, VMCNT(0));
    KTILE(23, 1, (void)0, (void)0, (void)0, (void)0, (void)0);

    // ---- epilogue: bias + relu, store bf16 Y[p][row][512] ----
    float bc[2][2];
#pragma unroll
    for (int nh = 0; nh < 2; ++nh)
#pragma unroll
        for (int j = 0; j < 2; ++j)
            bc[nh][j] = bias[oB + nh * 128 + (wn * 2 + j) * 16 + lr];

#define STORE_Q(ACC, MH, NH) do { \
    _Pragma("unroll") for (int i_ = 0; i_ < 4; ++i_) \
    _Pragma("unroll") for (int j_ = 0; j_ < 2; ++j_) { \
        int col_ = oB + (NH)*128 + (wn*2 + j_)*16 + lr; \
        _Pragma("unroll") for (int r_ = 0; r_ < 4; ++r_) { \
            int row_ = rowBase + (MH)*128 + (wm*4 + i_)*16 + kq*4 + r_; \
            Y[((size_t)p * NRR + row_) * H_ + col_] = (bf16)fmaxf(ACC[i_][j_][r_] + bc[NH][j_], 0.f); \
        } } \
} while (0)

    STORE_Q(acc00, 0, 0); STORE_Q(acc01, 0, 1);
    STORE_Q(acc10, 1, 0); STORE_Q(acc11, 1, 1);

#undef STAGE_A
#undef STAGE_B
#undef LOAD_A
#undef LOAD_B
#undef MFMA_Q
#undef KTILE
#undef STORE_Q
}

// ---------------- batched LayerNorm (layer-0) -> padded xp1[p] ---------------
__global__ void k_ln_store(const bf16* __restrict__ Yin,
                           const float* __restrict__ g0, const float* __restrict__ g1,
                           const float* __restrict__ g2,
                           const float* __restrict__ bb0, const float* __restrict__ bb1,
                           const float* __restrict__ bb2, bf16* __restrict__ xp1) {
    int wid = threadIdx.x >> 6, lane = threadIdx.x & 63;
    int rg = blockIdx.x * 4 + wid;
    int p = rg >> 14, r = rg & (NRR - 1);
    const float* g   = (p == 0) ? g0 : (p == 1 ? g1 : g2);
    const float* bta = (p == 0) ? bb0 : (p == 1 ? bb1 : bb2);
    bf16x8 a = *(const bf16x8*)(Yin + ((size_t)p * NRR + r) * H_ + lane * 8);
    float f[8];
#pragma unroll
    for (int i = 0; i < 8; ++i) f[i] = (float)a[i];
    float s1 = 0.f, s2 = 0.f;
#pragma unroll
    for (int i = 0; i < 8; ++i) { s1 += f[i]; s2 += f[i] * f[i]; }
    for (int m = 1; m < 64; m <<= 1) { s1 += __shfl_xor(s1, m); s2 += __shfl_xor(s2, m); }
    float mean = s1 * (1.f / H_);
    float var  = s2 * (1.f / H_) - mean * mean;
    float rs   = rsqrtf(var + EPS_);
    const f32x4* gp = (const f32x4*)g;
    const f32x4* bp = (const f32x4*)bta;
    f32x4 ga = gp[lane * 2], gb = gp[lane * 2 + 1];
    f32x4 ba = bp[lane * 2], bbv = bp[lane * 2 + 1];
    bf16x8 o;
    o[0] = (bf16)((f[0] - mean) * rs * ga[0] + ba[0]);
    o[1] = (bf16)((f[1] - mean) * rs * ga[1] + ba[1]);
    o[2] = (bf16)((f[2] - mean) * rs * ga[2] + ba[2]);
    o[3] = (bf16)((f[3] - mean) * rs * ga[3] + ba[3]);
    o[4] = (bf16)((f[4] - mean) * rs * gb[0] + bbv[0]);
    o[5] = (bf16)((f[5] - mean) * rs * gb[1] + bbv[1]);
    o[6] = (bf16)((f[6] - mean) * rs * gb[2] + bbv[2]);
    o[7] = (bf16)((f[7] - mean) * rs * gb[3] + bbv[3]);
    int bb = r >> 9, t = r & (T_ - 1);
    *(bf16x8*)(xp1 + (size_t)p * XPE + ((size_t)(bb * TP_ + t + 1)) * H_ + lane * 8) = o;
}

// ---------------- batched LayerNorm (layer-1) + linear H->1 + mask -----------
__global__ void k_ln_linear(const bf16* __restrict__ Yin,
                            const float* __restrict__ g0, const float* __restrict__ g1,
                            const float* __restrict__ g2,
                            const float* __restrict__ bb0, const float* __restrict__ bb1,
                            const float* __restrict__ bb2,
                            const float* __restrict__ w0p, const float* __restrict__ w1p,
                            const float* __restrict__ w2p,
                            const float* __restrict__ lb0, const float* __restrict__ lb1,
                            const float* __restrict__ lb2,
                            const unsigned char* __restrict__ mask,
                            float* __restrict__ o0, float* __restrict__ o1,
                            float* __restrict__ o2) {
    int wid = threadIdx.x >> 6, lane = threadIdx.x & 63;
    int rg = blockIdx.x * 4 + wid;
    int p = rg >> 14, r = rg & (NRR - 1);
    const float* g   = ((p == 0) ? g0 : (p == 1 ? g1 : g2)) + H_;
    const float* bta = ((p == 0) ? bb0 : (p == 1 ? bb1 : bb2)) + H_;
    const float* lw  = (p == 0) ? w0p : (p == 1 ? w1p : w2p);
    const float* lb  = (p == 0) ? lb0 : (p == 1 ? lb1 : lb2);
    float*       op  = (p == 0) ? o0 : (p == 1 ? o1 : o2);
    bf16x8 a = *(const bf16x8*)(Yin + ((size_t)p * NRR + r) * H_ + lane * 8);
    float f[8];
#pragma unroll
    for (int i = 0; i < 8; ++i) f[i] = (float)a[i];
    float s1 = 0.f, s2 = 0.f;
#pragma unroll
    for (int i = 0; i < 8; ++i) { s1 += f[i]; s2 += f[i] * f[i]; }
    for (int m = 1; m < 64; m <<= 1) { s1 += __shfl_xor(s1, m); s2 += __shfl_xor(s2, m); }
    float mean = s1 * (1.f / H_);
    float var  = s2 * (1.f / H_) - mean * mean;
    float rs   = rsqrtf(var + EPS_);
    const f32x4* gp = (const f32x4*)g;
    const f32x4* bp = (const f32x4*)bta;
    const f32x4* wp = (const f32x4*)lw;
    f32x4 ga = gp[lane * 2], gb = gp[lane * 2 + 1];
    f32x4 ba = bp[lane * 2], bbv = bp[lane * 2 + 1];
    f32x4 wa = wp[lane * 2], wb = wp[lane * 2 + 1];
    float s = ((f[0] - mean) * rs * ga[0] + ba[0]) * wa[0]
            + ((f[1] - mean) * rs * ga[1] + ba[1]) * wa[1]
            + ((f[2] - mean) * rs * ga[2] + ba[2]) * wa[2]
            + ((f[3] - mean) * rs * ga[3] + ba[3]) * wa[3]
            + ((f[4] - mean) * rs * gb[0] + bbv[0]) * wb[0]
            + ((f[5] - mean) * rs * gb[1] + bbv[1]) * wb[1]
            + ((f[6] - mean) * rs * gb[2] + bbv[2]) * wb[2]
            + ((f[7] - mean) * rs * gb[3] + bbv[3]) * wb[3];
    for (int m = 1; m < 64; m <<= 1) s += __shfl_xor(s, m);
    if (lane == 0) op[r] = mask[r] ? 0.f : (s + lb[0]);
}

extern "C" void kernel_launch(void* const* d_in, const int* in_sizes, int n_in,
                              void* d_out, int out_size, void* d_ws, size_t ws_size,
                              hipStream_t stream) {
    const float* x  = (const float*)d_in[0];
    const unsigned char* mask = (const unsigned char*)d_in[1];
    const int*   dur = (const int*)d_in[2];
    const float* pt  = (const float*)d_in[3];
    const float* et  = (const float*)d_in[4];
    const float* cw[3]    = {(const float*)d_in[6],  (const float*)d_in[12], (const float*)d_in[18]};
    const float* cb[3]    = {(const float*)d_in[7],  (const float*)d_in[13], (const float*)d_in[19]};
    const float* lg[3]    = {(const float*)d_in[8],  (const float*)d_in[14], (const float*)d_in[20]};
    const float* lbn[3]   = {(const float*)d_in[9],  (const float*)d_in[15], (const float*)d_in[21]};
    const float* lw[3]    = {(const float*)d_in[10], (const float*)d_in[16], (const float*)d_in[22]};
    const float* lbias[3] = {(const float*)d_in[11], (const float*)d_in[17], (const float*)d_in[23]};
    const float* pbins = (const float*)d_in[24];
    const float* ebins = (const float*)d_in[25];
    const float* pemb  = (const float*)d_in[26];
    const float* eemb  = (const float*)d_in[27];

    float* out0 = (float*)d_out;
    const size_t OUT0 = (size_t)B_ * L_ * H_;
    float* pitch_out  = out0 + OUT0;
    float* energy_out = pitch_out + NRR;
    float* logd_out   = energy_out + NRR;
    float* mel_out    = logd_out + NRR;

    char* ws = (char*)d_ws;
    bf16*  wc   = (bf16*)ws;
    bf16*  xp0  = (bf16*)(ws + WC_BYTES);
    bf16*  xp1  = (bf16*)(ws + WC_BYTES + XP_BYTES);          // 3 buffers
    bf16*  y    = (bf16*)(ws + WC_BYTES + 4 * XP_BYTES);      // [3][NRR][512]
    int*   csum = (int*)(ws + WC_BYTES + 4 * XP_BYTES + Y_BYTES);

    k_prep_wc<<<(6 * H_ * KC_ + 255) / 256, 256, 0, stream>>>(cw[0], cw[1], cw[2], wc);
    k_pad<<<B_ * TP_ / 4, 256, 0, stream>>>(x, xp0, xp1);
    k_scan<<<B_, T_, 0, stream>>>(dur, csum, mel_out);
    k_gather<<<B_ * L_ / 4, 256, 0, stream>>>(x, pemb, eemb, pt, et, pbins, ebins, csum, out0);

    k_gemm<0><<<384, 512, 0, stream>>>(xp0, wc, cb[0], cb[1], cb[2], y);
    k_ln_store<<<3 * NRR / 4, 256, 0, stream>>>(y, lg[0], lg[1], lg[2],
                                                lbn[0], lbn[1], lbn[2], xp1);
    k_gemm<1><<<384, 512, 0, stream>>>(xp1, wc, cb[0], cb[1], cb[2], y);
    k_ln_linear<<<3 * NRR / 4, 256, 0, stream>>>(y, lg[0], lg[1], lg[2],
                                                 lbn[0], lbn[1], lbn[2],
                                                 lw[0], lw[1], lw[2],
                                                 lbias[0], lbias[1], lbias[2],
                                                 mask, logd_out, pitch_out, energy_out);
}

// Round 8
// 246.056 us; speedup vs baseline: 1.1380x; 1.1380x over previous
//
#include <hip/hip_runtime.h>
#include <hip/hip_bf16.h>

#define B_ 32
#define T_ 512
#define TP_ 514          /* padded rows per batch */
#define L_ 2048
#define H_ 512
#define NRR (B_*T_)      /* 16384 rows */
#define KC_ 1536         /* 3*H */
#define NB_ 256
#define EPS_ 1e-5f
#define XPE ((size_t)B_ * TP_ * H_)   /* elems per padded buffer */

typedef __bf16 bf16;
typedef __bf16 bf16x8 __attribute__((ext_vector_type(8)));
typedef float f32x4 __attribute__((ext_vector_type(4)));

static const size_t WC_BYTES  = (size_t)6 * H_ * KC_ * 2;       // 9,437,184
static const size_t XP_BYTES  = XPE * 2;                        // 16,842,752
static const size_t Y_BYTES   = (size_t)3 * NRR * H_ * 2;       // 50,331,648

__device__ __forceinline__ void gload16(const void* g, void* l) {
    __builtin_amdgcn_global_load_lds(
        (const __attribute__((address_space(1))) unsigned int*)g,
        (__attribute__((address_space(3))) unsigned int*)l, 16, 0, 0);
}

// ---------------- weight repack: w[i][o][c][k] -> Wc[m][o][k*H + c] (bf16) ----
__global__ void k_prep_wc(const float* __restrict__ wd, const float* __restrict__ wp,
                          const float* __restrict__ we, bf16* __restrict__ wc) {
    int e = blockIdx.x * 256 + threadIdx.x;
    if (e >= 6 * H_ * KC_) return;
    int m   = e / (H_ * KC_);
    int rem = e % (H_ * KC_);
    int o  = rem / KC_;
    int r2 = rem % KC_;
    int k  = r2 / H_;
    int c  = r2 % H_;
    int p = m >> 1, i = m & 1;
    const float* w = (p == 0) ? wd : (p == 1 ? wp : we);
    float v = w[((size_t)i * H_ * H_ + (size_t)o * H_ + c) * 3 + k];
    wc[e] = (bf16)v;
}

// ---------------- padded bf16 input + zero pad rows of the 3 xp1 buffers -----
__global__ void k_pad(const float* __restrict__ x, bf16* __restrict__ xp0,
                      bf16* __restrict__ xp1) {
    int wid = threadIdx.x >> 6, lane = threadIdx.x & 63;
    int row = blockIdx.x * 4 + wid;               // 0 .. 32*514-1
    int b = row / TP_, tp = row % TP_;
    bf16* d0 = xp0 + (size_t)row * H_ + lane * 8;
    if (tp == 0 || tp == TP_ - 1) {
        bf16x8 z;
#pragma unroll
        for (int i = 0; i < 8; ++i) z[i] = (bf16)0.0f;
        *(bf16x8*)d0 = z;
#pragma unroll
        for (int p = 0; p < 3; ++p)
            *(bf16x8*)(xp1 + p * XPE + (size_t)row * H_ + lane * 8) = z;
    } else {
        const f32x4* p = (const f32x4*)(x + ((size_t)(b * T_ + tp - 1)) * H_ + lane * 8);
        f32x4 u = p[0], v = p[1];
        bf16x8 o;
        o[0] = (bf16)u[0]; o[1] = (bf16)u[1]; o[2] = (bf16)u[2]; o[3] = (bf16)u[3];
        o[4] = (bf16)v[0]; o[5] = (bf16)v[1]; o[6] = (bf16)v[2]; o[7] = (bf16)v[3];
        *(bf16x8*)d0 = o;
    }
}

// ---------------- per-batch inclusive scan of durations ----------------------
__global__ void k_scan(const int* __restrict__ dur, int* __restrict__ csum,
                       float* __restrict__ mel_out) {
    int b = blockIdx.x, t = threadIdx.x;
    __shared__ int s[T_];
    s[t] = dur[b * T_ + t];
    __syncthreads();
    for (int off = 1; off < T_; off <<= 1) {
        int v = (t >= off) ? s[t - off] : 0;
        __syncthreads();
        s[t] += v;
        __syncthreads();
    }
    csum[b * T_ + t] = s[t];
    if (t == T_ - 1) mel_out[b] = (float)((s[t] < L_) ? s[t] : L_);
}

// -------- length regulate + inline bucketize + (x + p_emb + e_emb) gather ----
__global__ void k_gather(const float* __restrict__ x, const float* __restrict__ pemb,
                         const float* __restrict__ eemb, const float* __restrict__ pt,
                         const float* __restrict__ et, const float* __restrict__ pbins,
                         const float* __restrict__ ebins, const int* __restrict__ csum,
                         float* __restrict__ out) {
    int bi = blockIdx.x;
    int b  = bi >> 9;
    int l0 = (bi & 511) << 2;
    __shared__ int cs[T_];
    __shared__ float pb[NB_ - 1], eb[NB_ - 1];
    cs[threadIdx.x]       = csum[b * T_ + threadIdx.x];
    cs[threadIdx.x + 256] = csum[b * T_ + threadIdx.x + 256];
    if (threadIdx.x < NB_ - 1) {
        pb[threadIdx.x] = pbins[threadIdx.x];
        eb[threadIdx.x] = ebins[threadIdx.x];
    }
    __syncthreads();
    int wid = threadIdx.x >> 6, lane = threadIdx.x & 63;
    int l = l0 + wid;
    int mel = cs[T_ - 1]; if (mel > L_) mel = L_;
    float* op = out + ((size_t)(b * L_ + l)) * H_ + lane * 8;
    if (l >= mel) {
        f32x4 z = {0.f, 0.f, 0.f, 0.f};
        ((f32x4*)op)[0] = z;
        ((f32x4*)op)[1] = z;
        return;
    }
    int lo = 0, hi = T_;
    while (lo < hi) { int mid = (lo + hi) >> 1; if (cs[mid] <= l) lo = mid + 1; else hi = mid; }
    int idx = (lo < T_ - 1) ? lo : (T_ - 1);
    int rr = b * T_ + idx;
    float pv = pt[rr], ev = et[rr];
    int pi, ei;
    { int a = 0, c = NB_ - 1; while (a < c) { int mid = (a + c) >> 1; if (pb[mid] < pv) a = mid + 1; else c = mid; } pi = a; }
    { int a = 0, c = NB_ - 1; while (a < c) { int mid = (a + c) >> 1; if (eb[mid] < ev) a = mid + 1; else c = mid; } ei = a; }
    const f32x4* xp = (const f32x4*)(x    + (size_t)rr * H_ + lane * 8);
    const f32x4* pp = (const f32x4*)(pemb + (size_t)pi * H_ + lane * 8);
    const f32x4* ep = (const f32x4*)(eemb + (size_t)ei * H_ + lane * 8);
    ((f32x4*)op)[0] = xp[0] + pp[0] + ep[0];
    ((f32x4*)op)[1] = xp[1] + pp[1] + ep[1];
}

// ============ conv-aware tiled GEMM with tap-reuse ===========================
// BM=128, BN=128, H-chunk=64; 4 waves (2Mx2N), per-wave 64x64 out.
// A staged ONCE per H-chunk as a 136-row slab (t0..t0+135 padded); the 3 conv
// taps read row-shifted fragments from the same LDS tile -> 96 MFMA/wave per
// barrier-pair (3x m97), A-staging cut 3x, 8 K-steps instead of 24.
// T2 both-sides swizzle: stage key = dest-row&7, read key = (read-row)&7.
// T1: xcd = bid&7; per-XCD: 16 rowblks x all 12 colblks, rowblk-inner
//     (A slice 2.1MB L2-resident; W 393KB live per colblk stretch).
// colblk 0..11: p = colblk>>2, col-base = (colblk&3)*128 (both layers).
template<int LAYER>
__global__ __launch_bounds__(256)
void k_gemm(const bf16* __restrict__ Xp, const bf16* __restrict__ Wall,
            const float* __restrict__ cb0, const float* __restrict__ cb1,
            const float* __restrict__ cb2, bf16* __restrict__ Y) {
    __shared__ bf16 lA[136 * 64];        // 17,408 B
    __shared__ bf16 lB[3 * 128 * 64];    // 49,152 B

    int bid = blockIdx.x;
    int xcd = bid & 7, idx = bid >> 3;   // 1536 blocks: idx 0..191
    int colblk = idx >> 4;               // 0..11  (colblk-major per XCD)
    int rowblk = xcd * 16 + (idx & 15);  // 0..127
    int p  = colblk >> 2;
    int oB = (colblk & 3) * 128;
    int rowBase = rowblk * 128;

    const bf16* A = (LAYER == 0) ? Xp : (Xp + (size_t)p * XPE);
    const bf16* W = Wall + ((size_t)(2 * p + LAYER) * H_ + oB) * KC_;
    const float* cbp  = (p == 0) ? cb0 : (p == 1 ? cb1 : cb2);
    const float* bias = cbp + LAYER * H_;

    int tid = threadIdx.x;
    int wid = tid >> 6, lane = tid & 63;
    int wm = wid >> 1, wn = wid & 1;     // 2M x 2N waves
    int lr = lane & 15, kq = lane >> 4;
    int rsub = lane >> 3;
    int csw  = ((lane & 7) ^ rsub) << 3; // T2 pre-swizzled source col (16B units)
    int b = rowBase >> 9, t0 = rowBase & (T_ - 1);
    // lA row i holds padded row (b*TP + t0) + i ; output row r, tap k reads i = r+k
    const bf16* Abase = A + ((size_t)(b * TP_ + t0)) * H_;

    f32x4 acc[4][4];
#pragma unroll
    for (int m = 0; m < 4; ++m)
#pragma unroll
        for (int n = 0; n < 4; ++n) acc[m][n] = (f32x4){0.f, 0.f, 0.f, 0.f};

    for (int s = 0; s < 8; ++s) {
        int c0 = s * 64;
        // ---- stage A: 17 groups of 8 rows (136 rows) ----
#pragma unroll
        for (int q = 0; q < 5; ++q) {
            int g = q * 4 + wid;
            if (g < 17)
                gload16(Abase + (size_t)(g * 8 + rsub) * H_ + c0 + csw, &lA[g * 8 * 64]);
        }
        // ---- stage B: 3 taps x 16 groups of 8 rows ----
#pragma unroll
        for (int tap = 0; tap < 3; ++tap)
#pragma unroll
            for (int q = 0; q < 4; ++q) {
                int g = q * 4 + wid;
                gload16(W + (size_t)(g * 8 + rsub) * KC_ + tap * H_ + c0 + csw,
                        &lB[(tap * 128 + g * 8) * 64]);
            }
        __syncthreads();   // compiler drains vmcnt before barrier

#pragma unroll
        for (int tap = 0; tap < 3; ++tap) {
            bf16x8 af[4][2], bfr[4][2];
            int ka = (lr + tap) & 7, kb = lr & 7;
#pragma unroll
            for (int m = 0; m < 4; ++m)
#pragma unroll
                for (int kk = 0; kk < 2; ++kk)
                    af[m][kk] = *(const bf16x8*)&lA[(wm * 64 + m * 16 + lr + tap) * 64 +
                                                    ((((kk * 4 + kq) ^ ka)) << 3)];
#pragma unroll
            for (int n = 0; n < 4; ++n)
#pragma unroll
                for (int kk = 0; kk < 2; ++kk)
                    bfr[n][kk] = *(const bf16x8*)&lB[(tap * 128 + wn * 64 + n * 16 + lr) * 64 +
                                                     ((((kk * 4 + kq) ^ kb)) << 3)];
#pragma unroll
            for (int m = 0; m < 4; ++m)
#pragma unroll
                for (int n = 0; n < 4; ++n)
#pragma unroll
                    for (int kk = 0; kk < 2; ++kk)
                        acc[m][n] = __builtin_amdgcn_mfma_f32_16x16x32_bf16(
                            af[m][kk], bfr[n][kk], acc[m][n], 0, 0, 0);
        }
        __syncthreads();
    }

    // D layout: col = lane&15 (o), row = 4*(lane>>4) + reg
#pragma unroll
    for (int n = 0; n < 4; ++n) {
        int o = oB + wn * 64 + n * 16 + lr;
        float bi = bias[o];
#pragma unroll
        for (int m = 0; m < 4; ++m) {
            int row = rowBase + wm * 64 + m * 16 + 4 * kq;
#pragma unroll
            for (int r = 0; r < 4; ++r)
                Y[((size_t)p * NRR + row + r) * H_ + o] = (bf16)fmaxf(acc[m][n][r] + bi, 0.f);
        }
    }
}

// ---------------- batched LayerNorm (layer-0) -> padded xp1[p] ---------------
__global__ void k_ln_store(const bf16* __restrict__ Yin,
                           const float* __restrict__ g0, const float* __restrict__ g1,
                           const float* __restrict__ g2,
                           const float* __restrict__ bb0, const float* __restrict__ bb1,
                           const float* __restrict__ bb2, bf16* __restrict__ xp1) {
    int wid = threadIdx.x >> 6, lane = threadIdx.x & 63;
    int rg = blockIdx.x * 4 + wid;
    int p = rg >> 14, r = rg & (NRR - 1);
    const float* g   = (p == 0) ? g0 : (p == 1 ? g1 : g2);
    const float* bta = (p == 0) ? bb0 : (p == 1 ? bb1 : bb2);
    bf16x8 a = *(const bf16x8*)(Yin + ((size_t)p * NRR + r) * H_ + lane * 8);
    float f[8];
#pragma unroll
    for (int i = 0; i < 8; ++i) f[i] = (float)a[i];
    float s1 = 0.f, s2 = 0.f;
#pragma unroll
    for (int i = 0; i < 8; ++i) { s1 += f[i]; s2 += f[i] * f[i]; }
    for (int m = 1; m < 64; m <<= 1) { s1 += __shfl_xor(s1, m); s2 += __shfl_xor(s2, m); }
    float mean = s1 * (1.f / H_);
    float var  = s2 * (1.f / H_) - mean * mean;
    float rs   = rsqrtf(var + EPS_);
    const f32x4* gp = (const f32x4*)g;
    const f32x4* bp = (const f32x4*)bta;
    f32x4 ga = gp[lane * 2], gb = gp[lane * 2 + 1];
    f32x4 ba = bp[lane * 2], bbv = bp[lane * 2 + 1];
    bf16x8 o;
    o[0] = (bf16)((f[0] - mean) * rs * ga[0] + ba[0]);
    o[1] = (bf16)((f[1] - mean) * rs * ga[1] + ba[1]);
    o[2] = (bf16)((f[2] - mean) * rs * ga[2] + ba[2]);
    o[3] = (bf16)((f[3] - mean) * rs * ga[3] + ba[3]);
    o[4] = (bf16)((f[4] - mean) * rs * gb[0] + bbv[0]);
    o[5] = (bf16)((f[5] - mean) * rs * gb[1] + bbv[1]);
    o[6] = (bf16)((f[6] - mean) * rs * gb[2] + bbv[2]);
    o[7] = (bf16)((f[7] - mean) * rs * gb[3] + bbv[3]);
    int bb = r >> 9, t = r & (T_ - 1);
    *(bf16x8*)(xp1 + (size_t)p * XPE + ((size_t)(bb * TP_ + t + 1)) * H_ + lane * 8) = o;
}

// ---------------- batched LayerNorm (layer-1) + linear H->1 + mask -----------
__global__ void k_ln_linear(const bf16* __restrict__ Yin,
                            const float* __restrict__ g0, const float* __restrict__ g1,
                            const float* __restrict__ g2,
                            const float* __restrict__ bb0, const float* __restrict__ bb1,
                            const float* __restrict__ bb2,
                            const float* __restrict__ w0p, const float* __restrict__ w1p,
                            const float* __restrict__ w2p,
                            const float* __restrict__ lb0, const float* __restrict__ lb1,
                            const float* __restrict__ lb2,
                            const unsigned char* __restrict__ mask,
                            float* __restrict__ o0, float* __restrict__ o1,
                            float* __restrict__ o2) {
    int wid = threadIdx.x >> 6, lane = threadIdx.x & 63;
    int rg = blockIdx.x * 4 + wid;
    int p = rg >> 14, r = rg & (NRR - 1);
    const float* g   = ((p == 0) ? g0 : (p == 1 ? g1 : g2)) + H_;
    const float* bta = ((p == 0) ? bb0 : (p == 1 ? bb1 : bb2)) + H_;
    const float* lw  = (p == 0) ? w0p : (p == 1 ? w1p : w2p);
    const float* lb  = (p == 0) ? lb0 : (p == 1 ? lb1 : lb2);
    float*       op  = (p == 0) ? o0 : (p == 1 ? o1 : o2);
    bf16x8 a = *(const bf16x8*)(Yin + ((size_t)p * NRR + r) * H_ + lane * 8);
    float f[8];
#pragma unroll
    for (int i = 0; i < 8; ++i) f[i] = (float)a[i];
    float s1 = 0.f, s2 = 0.f;
#pragma unroll
    for (int i = 0; i < 8; ++i) { s1 += f[i]; s2 += f[i] * f[i]; }
    for (int m = 1; m < 64; m <<= 1) { s1 += __shfl_xor(s1, m); s2 += __shfl_xor(s2, m); }
    float mean = s1 * (1.f / H_);
    float var  = s2 * (1.f / H_) - mean * mean;
    float rs   = rsqrtf(var + EPS_);
    const f32x4* gp = (const f32x4*)g;
    const f32x4* bp = (const f32x4*)bta;
    const f32x4* wp = (const f32x4*)lw;
    f32x4 ga = gp[lane * 2], gb = gp[lane * 2 + 1];
    f32x4 ba = bp[lane * 2], bbv = bp[lane * 2 + 1];
    f32x4 wa = wp[lane * 2], wb = wp[lane * 2 + 1];
    float s = ((f[0] - mean) * rs * ga[0] + ba[0]) * wa[0]
            + ((f[1] - mean) * rs * ga[1] + ba[1]) * wa[1]
            + ((f[2] - mean) * rs * ga[2] + ba[2]) * wa[2]
            + ((f[3] - mean) * rs * ga[3] + ba[3]) * wa[3]
            + ((f[4] - mean) * rs * gb[0] + bbv[0]) * wb[0]
            + ((f[5] - mean) * rs * gb[1] + bbv[1]) * wb[1]
            + ((f[6] - mean) * rs * gb[2] + bbv[2]) * wb[2]
            + ((f[7] - mean) * rs * gb[3] + bbv[3]) * wb[3];
    for (int m = 1; m < 64; m <<= 1) s += __shfl_xor(s, m);
    if (lane == 0) op[r] = mask[r] ? 0.f : (s + lb[0]);
}

extern "C" void kernel_launch(void* const* d_in, const int* in_sizes, int n_in,
                              void* d_out, int out_size, void* d_ws, size_t ws_size,
                              hipStream_t stream) {
    const float* x  = (const float*)d_in[0];
    const unsigned char* mask = (const unsigned char*)d_in[1];
    const int*   dur = (const int*)d_in[2];
    const float* pt  = (const float*)d_in[3];
    const float* et  = (const float*)d_in[4];
    const float* cw[3]    = {(const float*)d_in[6],  (const float*)d_in[12], (const float*)d_in[18]};
    const float* cb[3]    = {(const float*)d_in[7],  (const float*)d_in[13], (const float*)d_in[19]};
    const float* lg[3]    = {(const float*)d_in[8],  (const float*)d_in[14], (const float*)d_in[20]};
    const float* lbn[3]   = {(const float*)d_in[9],  (const float*)d_in[15], (const float*)d_in[21]};
    const float* lw[3]    = {(const float*)d_in[10], (const float*)d_in[16], (const float*)d_in[22]};
    const float* lbias[3] = {(const float*)d_in[11], (const float*)d_in[17], (const float*)d_in[23]};
    const float* pbins = (const float*)d_in[24];
    const float* ebins = (const float*)d_in[25];
    const float* pemb  = (const float*)d_in[26];
    const float* eemb  = (const float*)d_in[27];

    float* out0 = (float*)d_out;
    const size_t OUT0 = (size_t)B_ * L_ * H_;
    float* pitch_out  = out0 + OUT0;
    float* energy_out = pitch_out + NRR;
    float* logd_out   = energy_out + NRR;
    float* mel_out    = logd_out + NRR;

    char* ws = (char*)d_ws;
    bf16*  wc   = (bf16*)ws;
    bf16*  xp0  = (bf16*)(ws + WC_BYTES);
    bf16*  xp1  = (bf16*)(ws + WC_BYTES + XP_BYTES);          // 3 buffers
    bf16*  y    = (bf16*)(ws + WC_BYTES + 4 * XP_BYTES);      // [3][NRR][512]
    int*   csum = (int*)(ws + WC_BYTES + 4 * XP_BYTES + Y_BYTES);

    k_prep_wc<<<(6 * H_ * KC_ + 255) / 256, 256, 0, stream>>>(cw[0], cw[1], cw[2], wc);
    k_pad<<<B_ * TP_ / 4, 256, 0, stream>>>(x, xp0, xp1);
    k_scan<<<B_, T_, 0, stream>>>(dur, csum, mel_out);
    k_gather<<<B_ * L_ / 4, 256, 0, stream>>>(x, pemb, eemb, pt, et, pbins, ebins, csum, out0);

    k_gemm<0><<<1536, 256, 0, stream>>>(xp0, wc, cb[0], cb[1], cb[2], y);
    k_ln_store<<<3 * NRR / 4, 256, 0, stream>>>(y, lg[0], lg[1], lg[2],
                                                lbn[0], lbn[1], lbn[2], xp1);
    k_gemm<1><<<1536, 256, 0, stream>>>(xp1, wc, cb[0], cb[1], cb[2], y);
    k_ln_linear<<<3 * NRR / 4, 256, 0, stream>>>(y, lg[0], lg[1], lg[2],
                                                 lbn[0], lbn[1], lbn[2],
                                                 lw[0], lw[1], lw[2],
                                                 lbias[0], lbias[1], lbias[2],
                                                 mask, logd_out, pitch_out, energy_out);
}